// Round 4
// baseline (1532.996 us; speedup 1.0000x reference)
//
#include <hip/hip_runtime.h>
#include <cstdint>
#include <cstddef>

#define B_ 4
#define T_ 12
#define N_ 10000
#define FIN_ 16
#define H_ 64
#define E_ 160000
#define BT_ (B_*T_)          // 48
#define ROWS_ (BT_*N_)       // 480000
#define GRU_ROWS_ (B_*N_)    // 40000
#define NWG_ (ROWS_/64)      // 7500
#define NWGQ_ (NWG_/8)       // 937
#define NWGR_ (NWG_%8)       // 4

__device__ __forceinline__ float sigmoidf_(float x){ return 1.0f/(1.0f + __expf(-x)); }
__device__ __forceinline__ float tanhf_(float x){
  float ax = fabsf(x);
  float e  = __expf(-2.0f*ax);
  float t  = (1.0f - e)/(1.0f + e);
  return copysignf(t, x);
}

// ---------------------------------------------------------------------------
// h = relu(x @ W_pre + b_pre)   : thread per row (480000 rows)
// ---------------------------------------------------------------------------
__global__ __launch_bounds__(256) void k_pre(const float* __restrict__ x,
    const float* __restrict__ Wp, const float* __restrict__ bp,
    float* __restrict__ A){
  __shared__ float sW[FIN_*H_];
  __shared__ float sb[H_];
  for (int i = threadIdx.x; i < FIN_*H_; i += 256) sW[i] = Wp[i];
  if (threadIdx.x < H_) sb[threadIdx.x] = bp[threadIdx.x];
  __syncthreads();
  int r = blockIdx.x*256 + threadIdx.x;
  if (r >= ROWS_) return;
  const float4* xr = reinterpret_cast<const float4*>(x + (size_t)r*FIN_);
  float4 xv[4];
  #pragma unroll
  for (int i=0;i<4;i++) xv[i] = xr[i];
  const float* xk = reinterpret_cast<const float*>(xv);
  float4 acc[16];
  #pragma unroll
  for (int j=0;j<16;j++) acc[j] = reinterpret_cast<const float4*>(sb)[j];
  #pragma unroll
  for (int k=0;k<16;k++){
    float a = xk[k];
    const float4* wr = reinterpret_cast<const float4*>(sW + k*H_);
    #pragma unroll
    for (int j=0;j<16;j++){
      float4 w = wr[j];
      acc[j].x = fmaf(a, w.x, acc[j].x);
      acc[j].y = fmaf(a, w.y, acc[j].y);
      acc[j].z = fmaf(a, w.z, acc[j].z);
      acc[j].w = fmaf(a, w.w, acc[j].w);
    }
  }
  float4* outp = reinterpret_cast<float4*>(A + (size_t)r*H_);
  #pragma unroll
  for (int j=0;j<16;j++){
    float4 o = acc[j];
    o.x = fmaxf(o.x, 0.f); o.y = fmaxf(o.y, 0.f);
    o.z = fmaxf(o.z, 0.f); o.w = fmaxf(o.w, 0.f);
    outp[j] = o;
  }
}

// ---------------------------------------------------------------------------
// weighted degree (by dst) + edge count (by dst)
// ---------------------------------------------------------------------------
__global__ void k_deg(const int* __restrict__ ei, const float* __restrict__ ew,
                      float* __restrict__ wdeg, int* __restrict__ cnt){
  int e = blockIdx.x*256 + threadIdx.x;
  if (e >= E_) return;
  int d = ei[E_ + e];
  atomicAdd(&wdeg[d], ew[e]);
  atomicAdd(&cnt[d], 1);
}

// exclusive scan of cnt -> rs[0..N], single block of 1024
__global__ __launch_bounds__(1024) void k_scan(const int* __restrict__ cnt,
                                               int* __restrict__ rs){
  __shared__ int sb[1024];
  int tid = threadIdx.x;
  int base = tid*10;
  int loc[10]; int s = 0;
  #pragma unroll
  for (int j=0;j<10;j++){
    loc[j] = s;
    int v = (base+j < N_) ? cnt[base+j] : 0;
    s += v;
  }
  sb[tid] = s;
  __syncthreads();
  for (int off=1; off<1024; off<<=1){
    int v = (tid >= off) ? sb[tid-off] : 0;
    __syncthreads();
    sb[tid] += v;
    __syncthreads();
  }
  int pre = (tid>0) ? sb[tid-1] : 0;
  #pragma unroll
  for (int j=0;j<10;j++){
    if (base+j <= N_) rs[base+j] = pre + loc[j];
  }
}

__global__ void k_dinv(const float* __restrict__ wdeg, float* __restrict__ dinv){
  int i = blockIdx.x*256 + threadIdx.x;
  if (i >= N_) return;
  float dg = wdeg[i];
  dinv[i] = (dg > 0.f) ? rsqrtf(dg) : 0.f;
}

// fill CSR (by dst): src_s[slot], w_s[slot] = normalized weight
__global__ void k_fill(const int* __restrict__ ei, const float* __restrict__ ew,
                       const float* __restrict__ dinv, const int* __restrict__ rs,
                       int* __restrict__ fillc, int* __restrict__ src_s,
                       float* __restrict__ w_s){
  int e = blockIdx.x*256 + threadIdx.x;
  if (e >= E_) return;
  int s = ei[e], d = ei[E_ + e];
  float wn = dinv[s]*ew[e]*dinv[d];
  int slot = rs[d] + atomicAdd(&fillc[d], 1);
  src_s[slot] = s;
  w_s[slot]  = wn;
}

// ---------------------------------------------------------------------------
// Fused layer: Aout = relu( (S@Ain)@W_lin + Ain@W_root + b )
// Uses (S@A)@W == S@(A@W) associativity: gather FIRST (into LDS), then GEMM.
// 64-row tile, 32KB LDS, chunked XCD swizzle, 8-deep gather, double-buffered A.
// ---------------------------------------------------------------------------
__global__ __launch_bounds__(256) void k_conv(const float* __restrict__ Ain,
    float* __restrict__ Aout, const float* __restrict__ Wl,
    const float* __restrict__ Wr, const float* __restrict__ bc,
    const int* __restrict__ rs, const int* __restrict__ src_s,
    const float* __restrict__ w_s){
  __shared__ float As[64*64];
  __shared__ float Ws[64*64];
  // bijective chunked XCD swizzle (m204): hardware round-robins blockIdx%8
  int xcd = blockIdx.x & 7;
  int pos = blockIdx.x >> 3;
  int base = (xcd < NWGR_) ? xcd*(NWGQ_+1) : NWGR_*(NWGQ_+1) + (xcd-NWGR_)*NWGQ_;
  int blk = base + pos;
  int tid = threadIdx.x;
  int rowbase = blk * 64;
  // stage Ain tile (swizzled) + W_root
  #pragma unroll
  for (int j=0;j<4;j++){
    int i = tid + j*256;
    int row = i >> 4, c4 = i & 15;
    float4 v = *reinterpret_cast<const float4*>(Ain + (size_t)(rowbase+row)*H_ + c4*4);
    *reinterpret_cast<float4*>(As + row*64 + ((c4*4) ^ (((row>>2)&15)<<2))) = v;
  }
  #pragma unroll
  for (int j=0;j<4;j++){
    int i = tid + j*256;
    int k = i >> 4, c4 = i & 15;
    *reinterpret_cast<float4*>(Ws + k*64 + c4*4) =
        *reinterpret_cast<const float4*>(Wr + k*H_ + c4*4);
  }
  __syncthreads();
  int rg = tid >> 3, part = tid & 7;
  float4 acc[2][2];
  #pragma unroll
  for (int r=0;r<2;r++){ acc[r][0] = make_float4(0,0,0,0); acc[r][1] = make_float4(0,0,0,0); }
  // root-GEMM
  #pragma unroll 4
  for (int k4=0;k4<16;k4++){
    float4 a[2];
    #pragma unroll
    for (int r=0;r<2;r++)
      a[r] = *reinterpret_cast<const float4*>(As + (rg*2+r)*64 + ((k4*4) ^ (((rg>>1)&15)<<2)));
    const float* af = reinterpret_cast<const float*>(a);
    #pragma unroll
    for (int kk=0;kk<4;kk++){
      #pragma unroll
      for (int c4=0;c4<2;c4++){
        float4 w = *reinterpret_cast<const float4*>(Ws + (k4*4+kk)*64 + part*4 + c4*32);
        #pragma unroll
        for (int r=0;r<2;r++){
          float av = af[r*4+kk];
          acc[r][c4].x = fmaf(av, w.x, acc[r][c4].x);
          acc[r][c4].y = fmaf(av, w.y, acc[r][c4].y);
          acc[r][c4].z = fmaf(av, w.z, acc[r][c4].z);
          acc[r][c4].w = fmaf(av, w.w, acc[r][c4].w);
        }
      }
    }
  }
  __syncthreads();   // all As/Ws reads done
  // reload Ws with W_lin (overlaps gather latency)
  #pragma unroll
  for (int j=0;j<4;j++){
    int i = tid + j*256;
    int k = i >> 4, c4 = i & 15;
    *reinterpret_cast<float4*>(Ws + k*64 + c4*4) =
        *reinterpret_cast<const float4*>(Wl + k*H_ + c4*4);
  }
  // gather G = S@Ain rows into As (overwrite, swizzled), wave per row
  int wv = tid >> 6, lane = tid & 63;
  for (int q=0;q<16;q++){
    int lr = wv*16 + q;
    int row = rowbase + lr;
    int bt = row / N_;
    int node = row - bt*N_;
    int start = rs[node], end = rs[node+1];
    const float* Bp = Ain + (size_t)bt*N_*H_;
    float g = 0.f;
    int e = start;
    for (; e+7 < end; e += 8){
      int ss[8]; float ww[8]; float vv[8];
      #pragma unroll
      for (int u=0;u<8;u++){ ss[u] = src_s[e+u]; ww[u] = w_s[e+u]; }
      #pragma unroll
      for (int u=0;u<8;u++) vv[u] = Bp[(size_t)ss[u]*H_ + lane];
      #pragma unroll
      for (int u=0;u<8;u++) g = fmaf(ww[u], vv[u], g);
    }
    for (; e+1 < end; e += 2){
      int s0 = src_s[e], s1 = src_s[e+1];
      float w0 = w_s[e], w1 = w_s[e+1];
      float v0 = Bp[(size_t)s0*H_ + lane];
      float v1 = Bp[(size_t)s1*H_ + lane];
      g = fmaf(w0, v0, g); g = fmaf(w1, v1, g);
    }
    if (e < end)
      g = fmaf(w_s[e], Bp[(size_t)src_s[e]*H_ + lane], g);
    As[lr*64 + (lane ^ (((lr>>2)&15)<<2))] = g;
  }
  __syncthreads();
  // lin-GEMM on gathered G, accumulate into acc
  #pragma unroll 4
  for (int k4=0;k4<16;k4++){
    float4 a[2];
    #pragma unroll
    for (int r=0;r<2;r++)
      a[r] = *reinterpret_cast<const float4*>(As + (rg*2+r)*64 + ((k4*4) ^ (((rg>>1)&15)<<2)));
    const float* af = reinterpret_cast<const float*>(a);
    #pragma unroll
    for (int kk=0;kk<4;kk++){
      #pragma unroll
      for (int c4=0;c4<2;c4++){
        float4 w = *reinterpret_cast<const float4*>(Ws + (k4*4+kk)*64 + part*4 + c4*32);
        #pragma unroll
        for (int r=0;r<2;r++){
          float av = af[r*4+kk];
          acc[r][c4].x = fmaf(av, w.x, acc[r][c4].x);
          acc[r][c4].y = fmaf(av, w.y, acc[r][c4].y);
          acc[r][c4].z = fmaf(av, w.z, acc[r][c4].z);
          acc[r][c4].w = fmaf(av, w.w, acc[r][c4].w);
        }
      }
    }
  }
  // epilogue: + bias, relu, store (straight from regs, coalesced)
  #pragma unroll
  for (int r=0;r<2;r++){
    size_t rb = (size_t)(rowbase + rg*2 + r) * H_;
    #pragma unroll
    for (int c4=0;c4<2;c4++){
      int col = part*4 + c4*32;
      float4 bv = *reinterpret_cast<const float4*>(bc + col);
      float4 v = acc[r][c4];
      v.x = fmaxf(v.x + bv.x, 0.f);
      v.y = fmaxf(v.y + bv.y, 0.f);
      v.z = fmaxf(v.z + bv.z, 0.f);
      v.w = fmaxf(v.w + bv.w, 0.f);
      *reinterpret_cast<float4*>(Aout + rb + col) = v;
    }
  }
}

// ---------------------------------------------------------------------------
// GRU over T=12. Block 1024 thr (16 waves); wave = 4 rows; lane = channel.
// LDS: W (96KB, XOR-swizzled rows) + per-wave x/h slices (32KB) = 128KB dyn.
// 16 waves/CU (vs 8 before) -> double the latency-hiding on VALU+LDS pipes.
// No barriers in the t-loop (per-wave slices, wave DS ops complete in order).
// ---------------------------------------------------------------------------
__global__ __launch_bounds__(1024) void k_gru(const float* __restrict__ A,
    const float* __restrict__ Wih, const float* __restrict__ Whh,
    const float* __restrict__ bih, const float* __restrict__ bhh,
    float* __restrict__ out){
  extern __shared__ float lds[];
  float* Wl = lds;                      // [384][64] swizzled; 0..191 ih, 192..383 hh
  int tid = threadIdx.x;
  int wv = tid >> 6;
  int lane = tid & 63;
  float* xs = lds + 24576 + wv*512;     // [4][64]
  float* hs = xs + 256;                 // [4][64]
  #pragma unroll
  for (int j=0;j<6;j++){
    int i = tid + j*1024;
    int g = i >> 4, c4 = i & 15;
    float4 v = (g < 192)
      ? *reinterpret_cast<const float4*>(Wih + g*H_ + c4*4)
      : *reinterpret_cast<const float4*>(Whh + (g-192)*H_ + c4*4);
    *reinterpret_cast<float4*>(Wl + g*64 + ((c4*4) ^ ((g&7)<<2))) = v;
  }
  __syncthreads();
  float hreg[4];
  #pragma unroll
  for (int r=0;r<4;r++){ hreg[r] = 0.f; hs[r*64 + lane] = 0.f; }

  int row0 = blockIdx.x*64 + wv*4;      // N_%4==0 -> wave rows share b
  int bb = row0 / N_;
  int nn0 = row0 - bb*N_;
  float bi[3], bh[3];
  #pragma unroll
  for (int s=0;s<3;s++){ bi[s] = bih[s*64 + lane]; bh[s] = bhh[s*64 + lane]; }
  int gxor = (lane & 7) << 2;
  int xr = lane >> 4, xc4 = lane & 15;  // x-staging slot

  for (int t=0; t<T_; t++){
    const float* Ab = A + ((size_t)(bb*T_ + t)*N_ + nn0)*H_;
    *reinterpret_cast<float4*>(xs + xr*64 + xc4*4) =
        *reinterpret_cast<const float4*>(Ab + (size_t)xr*H_ + xc4*4);

    float ai[3][4], ah[3][4];
    #pragma unroll
    for (int s=0;s<3;s++)
      #pragma unroll
      for (int r=0;r<4;r++){ ai[s][r] = bi[s]; ah[s][r] = bh[s]; }

    #pragma unroll 4
    for (int k4=0;k4<16;k4++){
      int kw = (k4*4) ^ gxor;
      float4 wi[3], wh[3];
      #pragma unroll
      for (int s=0;s<3;s++){
        wi[s] = *reinterpret_cast<const float4*>(Wl + (s*64 + lane)*64 + kw);
        wh[s] = *reinterpret_cast<const float4*>(Wl + ((s+3)*64 + lane)*64 + kw);
      }
      #pragma unroll
      for (int r=0;r<4;r++){
        float4 xw = *reinterpret_cast<const float4*>(xs + r*64 + k4*4);
        float4 hw = *reinterpret_cast<const float4*>(hs + r*64 + k4*4);
        #pragma unroll
        for (int s=0;s<3;s++){
          ai[s][r] = fmaf(wi[s].x, xw.x, ai[s][r]);
          ai[s][r] = fmaf(wi[s].y, xw.y, ai[s][r]);
          ai[s][r] = fmaf(wi[s].z, xw.z, ai[s][r]);
          ai[s][r] = fmaf(wi[s].w, xw.w, ai[s][r]);
          ah[s][r] = fmaf(wh[s].x, hw.x, ah[s][r]);
          ah[s][r] = fmaf(wh[s].y, hw.y, ah[s][r]);
          ah[s][r] = fmaf(wh[s].z, hw.z, ah[s][r]);
          ah[s][r] = fmaf(wh[s].w, hw.w, ah[s][r]);
        }
      }
    }
    #pragma unroll
    for (int r=0;r<4;r++){
      float rr = sigmoidf_(ai[0][r] + ah[0][r]);
      float zz = sigmoidf_(ai[1][r] + ah[1][r]);
      float ng = tanhf_(ai[2][r] + rr*ah[2][r]);
      float hn = (1.f - zz)*ng + zz*hreg[r];
      hreg[r] = hn;
      hs[r*64 + lane] = hn;
    }
  }
  #pragma unroll
  for (int r=0;r<4;r++)
    out[(size_t)(row0 + r)*H_ + lane] = hreg[r];
}

// ---------------------------------------------------------------------------
extern "C" void kernel_launch(void* const* d_in, const int* in_sizes, int n_in,
                              void* d_out, int out_size, void* d_ws, size_t ws_size,
                              hipStream_t stream){
  const float* x     = (const float*)d_in[0];
  const int*   ei    = (const int*)d_in[1];
  const float* ew    = (const float*)d_in[2];
  const float* Wpre  = (const float*)d_in[3];
  const float* bpre  = (const float*)d_in[4];
  const float* Wlin  = (const float*)d_in[5];
  const float* Wroot = (const float*)d_in[6];
  const float* bconv = (const float*)d_in[7];
  const float* Wih   = (const float*)d_in[8];
  const float* Whh   = (const float*)d_in[9];
  const float* bih   = (const float*)d_in[10];
  const float* bhh   = (const float*)d_in[11];
  float* out = (float*)d_out;

  float* ws   = (float*)d_ws;
  float* A0   = ws;                       // 30,720,000 f
  float* A1   = A0 + (size_t)ROWS_*H_;    // 30,720,000 f
  float* wdeg = A1 + (size_t)ROWS_*H_;    // N
  float* dinv = wdeg + N_;                // N
  float* w_s  = dinv + N_;                // E
  int*   cnt   = (int*)(w_s + E_);        // N
  int*   fillc = cnt + N_;                // N
  int*   rs    = fillc + N_;              // N+1
  int*   src_s = rs + (N_+1);             // E

  hipMemsetAsync(wdeg, 0, N_*sizeof(float), stream);
  hipMemsetAsync(cnt,  0, 2*N_*sizeof(int), stream);   // cnt + fillc contiguous

  k_pre<<<ROWS_/256, 256, 0, stream>>>(x, Wpre, bpre, A0);
  k_deg<<<E_/256, 256, 0, stream>>>(ei, ew, wdeg, cnt);
  k_scan<<<1, 1024, 0, stream>>>(cnt, rs);
  k_dinv<<<(N_+255)/256, 256, 0, stream>>>(wdeg, dinv);
  k_fill<<<E_/256, 256, 0, stream>>>(ei, ew, dinv, rs, fillc, src_s, w_s);

  k_conv<<<NWG_, 256, 0, stream>>>(A0, A1, Wlin,          Wroot,          bconv,
                                   rs, src_s, w_s);
  k_conv<<<NWG_, 256, 0, stream>>>(A1, A0, Wlin + H_*H_,  Wroot + H_*H_,  bconv + H_,
                                   rs, src_s, w_s);

  hipFuncSetAttribute((const void*)k_gru,
      hipFuncAttributeMaxDynamicSharedMemorySize, 131072);
  k_gru<<<GRU_ROWS_/64, 1024, 131072, stream>>>(A0, Wih, Whh, bih, bhh, out);
}

// Round 5
// 1172.132 us; speedup vs baseline: 1.3079x; 1.3079x over previous
//
#include <hip/hip_runtime.h>
#include <cstdint>
#include <cstddef>

#define B_ 4
#define T_ 12
#define N_ 10000
#define FIN_ 16
#define H_ 64
#define E_ 160000
#define BT_ (B_*T_)          // 48
#define ROWS_ (BT_*N_)       // 480000
#define GRU_ROWS_ (B_*N_)    // 40000
#define PAD_ 68              // padded LDS row (floats) to break bank aliasing

__device__ __forceinline__ float sigmoidf_(float x){ return 1.0f/(1.0f + __expf(-x)); }
__device__ __forceinline__ float tanhf_(float x){
  float ax = fabsf(x);
  float e  = __expf(-2.0f*ax);
  float t  = (1.0f - e)/(1.0f + e);
  return copysignf(t, x);
}

// ---------------------------------------------------------------------------
// A[n][bt][h] = relu(x[bt][n] @ W_pre + b_pre)   (transposed output layout)
// thread per (bt,n) row: coalesced x read, 256B-chunk write
// ---------------------------------------------------------------------------
__global__ __launch_bounds__(256) void k_pre(const float* __restrict__ x,
    const float* __restrict__ Wp, const float* __restrict__ bp,
    float* __restrict__ A){
  __shared__ float sW[FIN_*H_];
  __shared__ float sb[H_];
  for (int i = threadIdx.x; i < FIN_*H_; i += 256) sW[i] = Wp[i];
  if (threadIdx.x < H_) sb[threadIdx.x] = bp[threadIdx.x];
  __syncthreads();
  int r = blockIdx.x*256 + threadIdx.x;
  if (r >= ROWS_) return;
  int bt = r / N_;
  int n  = r - bt*N_;
  const float4* xr = reinterpret_cast<const float4*>(x + (size_t)r*FIN_);
  float4 xv[4];
  #pragma unroll
  for (int i=0;i<4;i++) xv[i] = xr[i];
  const float* xk = reinterpret_cast<const float*>(xv);
  float4 acc[16];
  #pragma unroll
  for (int j=0;j<16;j++) acc[j] = reinterpret_cast<const float4*>(sb)[j];
  #pragma unroll
  for (int k=0;k<16;k++){
    float a = xk[k];
    const float4* wr = reinterpret_cast<const float4*>(sW + k*H_);
    #pragma unroll
    for (int j=0;j<16;j++){
      float4 w = wr[j];
      acc[j].x = fmaf(a, w.x, acc[j].x);
      acc[j].y = fmaf(a, w.y, acc[j].y);
      acc[j].z = fmaf(a, w.z, acc[j].z);
      acc[j].w = fmaf(a, w.w, acc[j].w);
    }
  }
  float4* outp = reinterpret_cast<float4*>(A + ((size_t)n*BT_ + bt)*H_);
  #pragma unroll
  for (int j=0;j<16;j++){
    float4 o = acc[j];
    o.x = fmaxf(o.x, 0.f); o.y = fmaxf(o.y, 0.f);
    o.z = fmaxf(o.z, 0.f); o.w = fmaxf(o.w, 0.f);
    outp[j] = o;
  }
}

// ---------------------------------------------------------------------------
// weighted degree (by dst) + edge count (by dst)
// ---------------------------------------------------------------------------
__global__ void k_deg(const int* __restrict__ ei, const float* __restrict__ ew,
                      float* __restrict__ wdeg, int* __restrict__ cnt){
  int e = blockIdx.x*256 + threadIdx.x;
  if (e >= E_) return;
  int d = ei[E_ + e];
  atomicAdd(&wdeg[d], ew[e]);
  atomicAdd(&cnt[d], 1);
}

// exclusive scan of cnt -> rs[0..N], single block of 1024
__global__ __launch_bounds__(1024) void k_scan(const int* __restrict__ cnt,
                                               int* __restrict__ rs){
  __shared__ int sb[1024];
  int tid = threadIdx.x;
  int base = tid*10;
  int loc[10]; int s = 0;
  #pragma unroll
  for (int j=0;j<10;j++){
    loc[j] = s;
    int v = (base+j < N_) ? cnt[base+j] : 0;
    s += v;
  }
  sb[tid] = s;
  __syncthreads();
  for (int off=1; off<1024; off<<=1){
    int v = (tid >= off) ? sb[tid-off] : 0;
    __syncthreads();
    sb[tid] += v;
    __syncthreads();
  }
  int pre = (tid>0) ? sb[tid-1] : 0;
  #pragma unroll
  for (int j=0;j<10;j++){
    if (base+j <= N_) rs[base+j] = pre + loc[j];
  }
}

__global__ void k_dinv(const float* __restrict__ wdeg, float* __restrict__ dinv){
  int i = blockIdx.x*256 + threadIdx.x;
  if (i >= N_) return;
  float dg = wdeg[i];
  dinv[i] = (dg > 0.f) ? rsqrtf(dg) : 0.f;
}

// fill CSR (by dst): src_s[slot], w_s[slot] = normalized weight
__global__ void k_fill(const int* __restrict__ ei, const float* __restrict__ ew,
                       const float* __restrict__ dinv, const int* __restrict__ rs,
                       int* __restrict__ fillc, int* __restrict__ src_s,
                       float* __restrict__ w_s){
  int e = blockIdx.x*256 + threadIdx.x;
  if (e >= E_) return;
  int s = ei[e], d = ei[E_ + e];
  float wn = dinv[s]*ew[e]*dinv[d];
  int slot = rs[d] + atomicAdd(&fillc[d], 1);
  src_s[slot] = s;
  w_s[slot]  = wn;
}

// ---------------------------------------------------------------------------
// Fused layer in [n][bt][h] layout. Block = one node n (256 thr, 4 waves).
//   G = sum_e w_e * Ain[src_e]        (48 x 64, gathered in regs -> LDS)
//   Aout[n] = relu( G@Wl + Ain[n]@Wr + b )
// Each edge's source read = 12KB contiguous (48 bt x 64 ch). W from global (L1).
// Wave w owns bt range [w*12, w*12+12); lane L -> (bt = +L/16, ch4 = (L%16)*4).
// ---------------------------------------------------------------------------
__global__ __launch_bounds__(256) void k_agg(const float* __restrict__ Ain,
    float* __restrict__ Aout, const float* __restrict__ Wl,
    const float* __restrict__ Wr, const float* __restrict__ bc,
    const int* __restrict__ rs, const int* __restrict__ src_s,
    const float* __restrict__ w_s){
  __shared__ float As[BT_*PAD_];   // node's own tile, padded rows
  __shared__ float Gs[BT_*PAD_];   // gathered tile, padded rows
  int n = blockIdx.x;
  int tid = threadIdx.x;
  // stage own tile (768 float4, padded rows)
  const float4* Ain4 = reinterpret_cast<const float4*>(Ain + (size_t)n*BT_*H_);
  #pragma unroll
  for (int j=0;j<3;j++){
    int i = tid + j*256;          // f4 index 0..767
    int bt = i >> 4, c4 = i & 15;
    *reinterpret_cast<float4*>(As + bt*PAD_ + c4*4) = Ain4[i];
  }
  // gather into regs (independent of As staging; no barrier needed yet)
  int wv = tid >> 6, L = tid & 63;
  int start = rs[n], end = rs[n+1];
  float4 acc[3];
  #pragma unroll
  for (int j=0;j<3;j++) acc[j] = make_float4(0.f,0.f,0.f,0.f);
  int e = start;
  for (; e+3 < end; e += 4){
    int   s0=src_s[e], s1=src_s[e+1], s2=src_s[e+2], s3=src_s[e+3];
    float w0=w_s[e],  w1=w_s[e+1],  w2=w_s[e+2],  w3=w_s[e+3];
    const float4* p0 = reinterpret_cast<const float4*>(Ain) + (size_t)s0*768 + wv*192 + L;
    const float4* p1 = reinterpret_cast<const float4*>(Ain) + (size_t)s1*768 + wv*192 + L;
    const float4* p2 = reinterpret_cast<const float4*>(Ain) + (size_t)s2*768 + wv*192 + L;
    const float4* p3 = reinterpret_cast<const float4*>(Ain) + (size_t)s3*768 + wv*192 + L;
    float4 v0[3], v1[3], v2[3], v3[3];
    #pragma unroll
    for (int j=0;j<3;j++){ v0[j]=p0[j*64]; v1[j]=p1[j*64]; v2[j]=p2[j*64]; v3[j]=p3[j*64]; }
    #pragma unroll
    for (int j=0;j<3;j++){
      acc[j].x = fmaf(w0, v0[j].x, acc[j].x); acc[j].y = fmaf(w0, v0[j].y, acc[j].y);
      acc[j].z = fmaf(w0, v0[j].z, acc[j].z); acc[j].w = fmaf(w0, v0[j].w, acc[j].w);
      acc[j].x = fmaf(w1, v1[j].x, acc[j].x); acc[j].y = fmaf(w1, v1[j].y, acc[j].y);
      acc[j].z = fmaf(w1, v1[j].z, acc[j].z); acc[j].w = fmaf(w1, v1[j].w, acc[j].w);
      acc[j].x = fmaf(w2, v2[j].x, acc[j].x); acc[j].y = fmaf(w2, v2[j].y, acc[j].y);
      acc[j].z = fmaf(w2, v2[j].z, acc[j].z); acc[j].w = fmaf(w2, v2[j].w, acc[j].w);
      acc[j].x = fmaf(w3, v3[j].x, acc[j].x); acc[j].y = fmaf(w3, v3[j].y, acc[j].y);
      acc[j].z = fmaf(w3, v3[j].z, acc[j].z); acc[j].w = fmaf(w3, v3[j].w, acc[j].w);
    }
  }
  for (; e < end; ++e){
    int s0 = src_s[e]; float w0 = w_s[e];
    const float4* p0 = reinterpret_cast<const float4*>(Ain) + (size_t)s0*768 + wv*192 + L;
    #pragma unroll
    for (int j=0;j<3;j++){
      float4 v = p0[j*64];
      acc[j].x = fmaf(w0, v.x, acc[j].x); acc[j].y = fmaf(w0, v.y, acc[j].y);
      acc[j].z = fmaf(w0, v.z, acc[j].z); acc[j].w = fmaf(w0, v.w, acc[j].w);
    }
  }
  // park G into LDS (padded, same chunk layout)
  {
    int bt0 = wv*12 + (L>>4), c4 = (L&15)*4;
    #pragma unroll
    for (int j=0;j<3;j++)
      *reinterpret_cast<float4*>(Gs + (bt0 + j*4)*PAD_ + c4) = acc[j];
  }
  __syncthreads();
  // dual GEMM: out = G@Wl + A@Wr  (W rows streamed from global/L1)
  int bt0 = wv*12 + (L>>4);
  int c4  = (L&15)*4;
  float4 bv = *reinterpret_cast<const float4*>(bc + c4);
  float4 out[3];
  #pragma unroll
  for (int j=0;j<3;j++) out[j] = bv;
  #pragma unroll 2
  for (int k4=0;k4<16;k4++){
    float4 wl[4], wr[4];
    #pragma unroll
    for (int i=0;i<4;i++){
      wl[i] = *reinterpret_cast<const float4*>(Wl + (k4*4+i)*H_ + c4);
      wr[i] = *reinterpret_cast<const float4*>(Wr + (k4*4+i)*H_ + c4);
    }
    #pragma unroll
    for (int j=0;j<3;j++){
      float4 g4 = *reinterpret_cast<const float4*>(Gs + (bt0 + j*4)*PAD_ + k4*4);
      float4 a4 = *reinterpret_cast<const float4*>(As + (bt0 + j*4)*PAD_ + k4*4);
      out[j].x = fmaf(g4.x, wl[0].x, out[j].x); out[j].y = fmaf(g4.x, wl[0].y, out[j].y);
      out[j].z = fmaf(g4.x, wl[0].z, out[j].z); out[j].w = fmaf(g4.x, wl[0].w, out[j].w);
      out[j].x = fmaf(g4.y, wl[1].x, out[j].x); out[j].y = fmaf(g4.y, wl[1].y, out[j].y);
      out[j].z = fmaf(g4.y, wl[1].z, out[j].z); out[j].w = fmaf(g4.y, wl[1].w, out[j].w);
      out[j].x = fmaf(g4.z, wl[2].x, out[j].x); out[j].y = fmaf(g4.z, wl[2].y, out[j].y);
      out[j].z = fmaf(g4.z, wl[2].z, out[j].z); out[j].w = fmaf(g4.z, wl[2].w, out[j].w);
      out[j].x = fmaf(g4.w, wl[3].x, out[j].x); out[j].y = fmaf(g4.w, wl[3].y, out[j].y);
      out[j].z = fmaf(g4.w, wl[3].z, out[j].z); out[j].w = fmaf(g4.w, wl[3].w, out[j].w);
      out[j].x = fmaf(a4.x, wr[0].x, out[j].x); out[j].y = fmaf(a4.x, wr[0].y, out[j].y);
      out[j].z = fmaf(a4.x, wr[0].z, out[j].z); out[j].w = fmaf(a4.x, wr[0].w, out[j].w);
      out[j].x = fmaf(a4.y, wr[1].x, out[j].x); out[j].y = fmaf(a4.y, wr[1].y, out[j].y);
      out[j].z = fmaf(a4.y, wr[1].z, out[j].z); out[j].w = fmaf(a4.y, wr[1].w, out[j].w);
      out[j].x = fmaf(a4.z, wr[2].x, out[j].x); out[j].y = fmaf(a4.z, wr[2].y, out[j].y);
      out[j].z = fmaf(a4.z, wr[2].z, out[j].z); out[j].w = fmaf(a4.z, wr[2].w, out[j].w);
      out[j].x = fmaf(a4.w, wr[3].x, out[j].x); out[j].y = fmaf(a4.w, wr[3].y, out[j].y);
      out[j].z = fmaf(a4.w, wr[3].z, out[j].z); out[j].w = fmaf(a4.w, wr[3].w, out[j].w);
    }
  }
  // relu + store (coalesced: wave writes 3x1KB contiguous chunks)
  float4* Aout4 = reinterpret_cast<float4*>(Aout + (size_t)n*BT_*H_);
  #pragma unroll
  for (int j=0;j<3;j++){
    float4 o = out[j];
    o.x = fmaxf(o.x, 0.f); o.y = fmaxf(o.y, 0.f);
    o.z = fmaxf(o.z, 0.f); o.w = fmaxf(o.w, 0.f);
    Aout4[wv*192 + j*64 + L] = o;
  }
}

// ---------------------------------------------------------------------------
// GRU over T=12 in [n][bt][h] layout. Block 1024 thr (16 waves); wave = 4 rows.
// LDS: W (96KB swizzled) + per-wave x/h slices (32KB) = 128KB dynamic.
// T14 prefetch: next-t x global load issued before the k4 loop.
// ---------------------------------------------------------------------------
__global__ __launch_bounds__(1024) void k_gru(const float* __restrict__ A,
    const float* __restrict__ Wih, const float* __restrict__ Whh,
    const float* __restrict__ bih, const float* __restrict__ bhh,
    float* __restrict__ out){
  extern __shared__ float lds[];
  float* Wl = lds;                      // [384][64] swizzled; 0..191 ih, 192..383 hh
  int tid = threadIdx.x;
  int wv = tid >> 6;
  int lane = tid & 63;
  float* xs = lds + 24576 + wv*512;     // [4][64]
  float* hs = xs + 256;                 // [4][64]
  #pragma unroll
  for (int j=0;j<6;j++){
    int i = tid + j*1024;
    int g = i >> 4, c4 = i & 15;
    float4 v = (g < 192)
      ? *reinterpret_cast<const float4*>(Wih + g*H_ + c4*4)
      : *reinterpret_cast<const float4*>(Whh + (g-192)*H_ + c4*4);
    *reinterpret_cast<float4*>(Wl + g*64 + ((c4*4) ^ ((g&7)<<2))) = v;
  }
  __syncthreads();
  float hreg[4];
  #pragma unroll
  for (int r=0;r<4;r++){ hreg[r] = 0.f; hs[r*64 + lane] = 0.f; }

  int row0 = blockIdx.x*64 + wv*4;      // row = b*N + n ; N%4==0 -> same b
  int bb = row0 / N_;
  int nn0 = row0 - bb*N_;
  float bi[3], bh[3];
  #pragma unroll
  for (int s=0;s<3;s++){ bi[s] = bih[s*64 + lane]; bh[s] = bhh[s*64 + lane]; }
  int gxor = (lane & 7) << 2;
  int xr = lane >> 4, xc4 = lane & 15;  // x-staging slot (row xr, f4 col xc4)
  // A[n][bt][h]: row (bb, nn0+xr), t -> offset ((nn0+xr)*48 + bb*12 + t)*64
  const float* Abase = A + ((size_t)(nn0 + xr)*BT_ + bb*T_)*H_;

  float4 xv = *reinterpret_cast<const float4*>(Abase + 0*H_ + xc4*4);
  for (int t=0; t<T_; t++){
    *reinterpret_cast<float4*>(xs + xr*64 + xc4*4) = xv;
    int tn = (t < T_-1) ? t+1 : t;
    float4 xv_n = *reinterpret_cast<const float4*>(Abase + (size_t)tn*H_ + xc4*4);

    float ai[3][4], ah[3][4];
    #pragma unroll
    for (int s=0;s<3;s++)
      #pragma unroll
      for (int r=0;r<4;r++){ ai[s][r] = bi[s]; ah[s][r] = bh[s]; }

    #pragma unroll 4
    for (int k4=0;k4<16;k4++){
      int kw = (k4*4) ^ gxor;
      float4 wi[3], wh[3];
      #pragma unroll
      for (int s=0;s<3;s++){
        wi[s] = *reinterpret_cast<const float4*>(Wl + (s*64 + lane)*64 + kw);
        wh[s] = *reinterpret_cast<const float4*>(Wl + ((s+3)*64 + lane)*64 + kw);
      }
      #pragma unroll
      for (int r=0;r<4;r++){
        float4 xw = *reinterpret_cast<const float4*>(xs + r*64 + k4*4);
        float4 hw = *reinterpret_cast<const float4*>(hs + r*64 + k4*4);
        #pragma unroll
        for (int s=0;s<3;s++){
          ai[s][r] = fmaf(wi[s].x, xw.x, ai[s][r]);
          ai[s][r] = fmaf(wi[s].y, xw.y, ai[s][r]);
          ai[s][r] = fmaf(wi[s].z, xw.z, ai[s][r]);
          ai[s][r] = fmaf(wi[s].w, xw.w, ai[s][r]);
          ah[s][r] = fmaf(wh[s].x, hw.x, ah[s][r]);
          ah[s][r] = fmaf(wh[s].y, hw.y, ah[s][r]);
          ah[s][r] = fmaf(wh[s].z, hw.z, ah[s][r]);
          ah[s][r] = fmaf(wh[s].w, hw.w, ah[s][r]);
        }
      }
    }
    #pragma unroll
    for (int r=0;r<4;r++){
      float rr = sigmoidf_(ai[0][r] + ah[0][r]);
      float zz = sigmoidf_(ai[1][r] + ah[1][r]);
      float ng = tanhf_(ai[2][r] + rr*ah[2][r]);
      float hn = (1.f - zz)*ng + zz*hreg[r];
      hreg[r] = hn;
      hs[r*64 + lane] = hn;
    }
    xv = xv_n;
  }
  #pragma unroll
  for (int r=0;r<4;r++)
    out[(size_t)(row0 + r)*H_ + lane] = hreg[r];
}

// ---------------------------------------------------------------------------
extern "C" void kernel_launch(void* const* d_in, const int* in_sizes, int n_in,
                              void* d_out, int out_size, void* d_ws, size_t ws_size,
                              hipStream_t stream){
  const float* x     = (const float*)d_in[0];
  const int*   ei    = (const int*)d_in[1];
  const float* ew    = (const float*)d_in[2];
  const float* Wpre  = (const float*)d_in[3];
  const float* bpre  = (const float*)d_in[4];
  const float* Wlin  = (const float*)d_in[5];
  const float* Wroot = (const float*)d_in[6];
  const float* bconv = (const float*)d_in[7];
  const float* Wih   = (const float*)d_in[8];
  const float* Whh   = (const float*)d_in[9];
  const float* bih   = (const float*)d_in[10];
  const float* bhh   = (const float*)d_in[11];
  float* out = (float*)d_out;

  float* ws   = (float*)d_ws;
  float* A0   = ws;                       // 30,720,000 f  [n][bt][h]
  float* A1   = A0 + (size_t)ROWS_*H_;    // 30,720,000 f
  float* wdeg = A1 + (size_t)ROWS_*H_;    // N
  float* dinv = wdeg + N_;                // N
  float* w_s  = dinv + N_;                // E
  int*   cnt   = (int*)(w_s + E_);        // N
  int*   fillc = cnt + N_;                // N
  int*   rs    = fillc + N_;              // N+1
  int*   src_s = rs + (N_+1);             // E
  // total ~247 MB (known-safe)

  hipMemsetAsync(wdeg, 0, N_*sizeof(float), stream);
  hipMemsetAsync(cnt,  0, 2*N_*sizeof(int), stream);   // cnt + fillc contiguous

  k_pre<<<ROWS_/256, 256, 0, stream>>>(x, Wpre, bpre, A0);
  k_deg<<<E_/256, 256, 0, stream>>>(ei, ew, wdeg, cnt);
  k_scan<<<1, 1024, 0, stream>>>(cnt, rs);
  k_dinv<<<(N_+255)/256, 256, 0, stream>>>(wdeg, dinv);
  k_fill<<<E_/256, 256, 0, stream>>>(ei, ew, dinv, rs, fillc, src_s, w_s);

  k_agg<<<N_, 256, 0, stream>>>(A0, A1, Wlin,         Wroot,         bconv,
                                rs, src_s, w_s);
  k_agg<<<N_, 256, 0, stream>>>(A1, A0, Wlin + H_*H_, Wroot + H_*H_, bconv + H_,
                                rs, src_s, w_s);

  hipFuncSetAttribute((const void*)k_gru,
      hipFuncAttributeMaxDynamicSharedMemorySize, 131072);
  k_gru<<<GRU_ROWS_/64, 1024, 131072, stream>>>(A0, Wih, Whh, bih, bhh, out);
}